// Round 4
// baseline (1100.714 us; speedup 1.0000x reference)
//
#include <hip/hip_runtime.h>
#include <stdint.h>

#define PN 4
#define NN 65536
#define DD 128
#define OO 128
#define EE 500000
#define MM 32768
#define NW 245       // WGs per block for bucketing: ceil(500000/2048)

typedef __attribute__((ext_vector_type(8))) short short8;
typedef __attribute__((ext_vector_type(4))) float floatx4;
typedef __attribute__((ext_vector_type(4))) float f4v;
typedef __attribute__((ext_vector_type(2))) unsigned u2v;

__device__ __forceinline__ unsigned short f2bf(float f) {
  unsigned u = __float_as_uint(f);
  u += 0x7fffu + ((u >> 16) & 1u);
  return (unsigned short)(u >> 16);
}
__device__ __forceinline__ float bfhi2f(unsigned u) { return __uint_as_float(u & 0xffff0000u); }
__device__ __forceinline__ float bflo2f(unsigned u) { return __uint_as_float(u << 16); }

// block b = s*4+d; diag blocks are b in {0,5,10,15}
__device__ __forceinline__ long rowbase(int b) {
  int diagb = (b + 4) / 5;
  int offb = b - diagb;
  return (long)diagb * NN + (long)offb * MM;
}
__device__ __forceinline__ int offidx(int b) { return b - (b + 4) / 5; }  // 0..11 for off-diag b

// ---- fp32 -> bf16 conversion of feats ----
__global__ __launch_bounds__(256) void cvt_kernel(const float* __restrict__ f,
                                                  unsigned short* __restrict__ o) {
  size_t i = (size_t)blockIdx.x * blockDim.x + threadIdx.x;
  f4v v = __builtin_nontemporal_load((const f4v*)f + i);
  uint2 r;
  r.x = ((unsigned)f2bf(v[1]) << 16) | f2bf(v[0]);
  r.y = ((unsigned)f2bf(v[3]) << 16) | f2bf(v[2]);
  ((uint2*)o)[i] = r;   // featsbf: keep cached (heavy downstream reuse)
}

// ---- pack W_self/W_neigh to bf16, col-major [mat][s][col][k] ----
__global__ __launch_bounds__(256) void packW_kernel(const float* __restrict__ Ws,
                                                    const float* __restrict__ Wn,
                                                    unsigned short* __restrict__ Wp) {
  int i = blockIdx.x * 256 + threadIdx.x;   // 2*4*128*128 = 131072
  int k = i & 127;
  int col = (i >> 7) & 127;
  int s = (i >> 14) & 3;
  int mat = i >> 16;
  const float* W = mat ? Wn : Ws;
  Wp[i] = f2bf(W[((size_t)s * DD + k) * OO + col]);
}

// ---- R1: per-WG coarse histogram (dst>>8), LDS only, coalesced matrix write ----
__global__ __launch_bounds__(256) void bucket_count(const int* __restrict__ edst,
                                                    int* __restrict__ mat) {
  __shared__ int hist[256];
  int b = blockIdx.y, w = blockIdx.x, t = threadIdx.x;
  hist[t] = 0;
  __syncthreads();
  size_t ebase = (size_t)b * EE;
#pragma unroll
  for (int k = 0; k < 8; ++k) {
    int e = w * 2048 + k * 256 + t;
    if (e < EE) atomicAdd(&hist[edst[ebase + e] >> 8], 1);
  }
  __syncthreads();
  mat[((size_t)b * NW + w) * 256 + t] = hist[t];
}

// ---- R2a: exclusive scan of mat over WG axis (per b,beta); totals per bucket ----
__global__ __launch_bounds__(256) void bucket_colscan(int* __restrict__ mat,
                                                      int* __restrict__ btot) {
  int t = threadIdx.x;
  int wid = blockIdx.x * 4 + (t >> 6);   // 4096 waves = 16 b * 256 beta
  int l = t & 63;
  int b = wid >> 8, beta = wid & 255;
  int run = 0;
  for (int c = 0; c < 4; ++c) {
    int w = c * 64 + l;
    size_t idx = ((size_t)b * NW + w) * 256 + beta;
    int v = (w < NW) ? mat[idx] : 0;
    int x = v;
#pragma unroll
    for (int off = 1; off < 64; off <<= 1) {
      int y = __shfl_up(x, off);
      if (l >= off) x += y;
    }
    if (w < NW) mat[idx] = run + x - v;
    run += __shfl(x, 63);
  }
  if (l == 0) btot[b * 256 + beta] = run;
}

// ---- R2b: per-block exclusive scan of 256 bucket totals -> bucket bases ----
__global__ __launch_bounds__(256) void bucket_base(const int* __restrict__ btot,
                                                   int* __restrict__ bbase) {
  __shared__ int sc[256];
  int b = blockIdx.x, t = threadIdx.x;
  int v = btot[b * 256 + t];
  sc[t] = v;
  __syncthreads();
  for (int off = 1; off < 256; off <<= 1) {
    int x = (t >= off) ? sc[t - off] : 0;
    __syncthreads();
    sc[t] += x;
    __syncthreads();
  }
  bbase[b * 256 + t] = sc[t] - v;
}

// ---- R3: scatter edges into coarse-bucket-sorted tmp via LDS cursors ----
__global__ __launch_bounds__(256) void bucket_scatter(const int* __restrict__ esrc,
                                                      const int* __restrict__ edst,
                                                      const int* __restrict__ mat,
                                                      const int* __restrict__ bbase,
                                                      uint2* __restrict__ tmp) {
  __shared__ int cur[256];
  int b = blockIdx.y, w = blockIdx.x, t = threadIdx.x;
  cur[t] = bbase[b * 256 + t] + mat[((size_t)b * NW + w) * 256 + t];
  __syncthreads();
  size_t ebase = (size_t)b * EE;
#pragma unroll
  for (int k = 0; k < 8; ++k) {
    int e = w * 2048 + k * 256 + t;
    if (e < EE) {
      int dv = __builtin_nontemporal_load(&edst[ebase + e]);
      int sv = __builtin_nontemporal_load(&esrc[ebase + e]);
      int p = atomicAdd(&cur[dv >> 8], 1);
      tmp[ebase + p] = (uint2){(unsigned)dv, (unsigned)sv};
    }
  }
}

// ---- R4: per (b, coarse bucket): fine CSR + deg + offs, all LDS-local ----
__global__ __launch_bounds__(256) void csr_build(const uint2* __restrict__ tmp,
                                                 const int* __restrict__ btot,
                                                 const int* __restrict__ bbase,
                                                 int* __restrict__ deg,
                                                 int* __restrict__ offs,
                                                 int* __restrict__ csr) {
  __shared__ int hist[256], sc[256], cur[256];
  int b = blockIdx.y, beta = blockIdx.x, t = threadIdx.x;
  int cnt = btot[b * 256 + beta];
  int segbase = bbase[b * 256 + beta];
  hist[t] = 0;
  __syncthreads();
  size_t tbase = (size_t)b * EE + segbase;
  for (int i = t; i < cnt; i += 256) atomicAdd(&hist[tmp[tbase + i].x & 255], 1);
  __syncthreads();
  sc[t] = hist[t];
  __syncthreads();
  for (int off = 1; off < 256; off <<= 1) {
    int x = (t >= off) ? sc[t - off] : 0;
    __syncthreads();
    sc[t] += x;
    __syncthreads();
  }
  int excl = sc[t] - hist[t];
  int v = beta * 256 + t;
  deg[b * NN + v] = hist[t];
  offs[b * NN + v] = segbase + excl;
  cur[t] = excl;
  __syncthreads();
  const u2v* tp = (const u2v*)tmp;
  for (int i = t; i < cnt; i += 256) {
    u2v pr = __builtin_nontemporal_load(tp + tbase + i);
    int p = atomicAdd(&cur[pr[0] & 255], 1);
    csr[(size_t)b * EE + segbase + p] = (int)pr[1];
  }
}

// ---- mean aggregation: one wave per dst row (R3: NT reverted, was -9us) ----
// At structural roofline: 834 MB random-256B fetch @ ~3.4 TB/s. Do not touch.
__global__ __launch_bounds__(256) void agg_kernel(const unsigned short* __restrict__ featsbf,
                                                  const int* __restrict__ csr,
                                                  const int* __restrict__ offs,
                                                  const int* __restrict__ deg,
                                                  unsigned short* __restrict__ hbuf) {
  int b = blockIdx.y;
  int s = b >> 2, d = b & 3;
  int num_dst = (s == d) ? NN : MM;
  int v = blockIdx.x * 4 + (threadIdx.x >> 6);
  if (v >= num_dst) return;
  int l = threadIdx.x & 63;
  const unsigned* F = (const unsigned*)(featsbf + (size_t)s * NN * DD);
  int o  = __builtin_amdgcn_readfirstlane(offs[b * NN + v]);
  int dg = __builtin_amdgcn_readfirstlane(deg[b * NN + v]);
  const int* cs = csr + (size_t)b * EE + o;   // wave-uniform pointer

  float alo[4] = {0.f, 0.f, 0.f, 0.f};
  float ahi[4] = {0.f, 0.f, 0.f, 0.f};

  for (int base = 0; base < dg; base += 64) {
    int rem = dg - base;
    int cnt = rem < 64 ? rem : 64;
    int myidx = (l < cnt) ? cs[base + l] : 0;
    int j = 0;
    for (; j + 8 <= cnt; j += 8) {
      unsigned p[8];
#pragma unroll
      for (int q = 0; q < 8; ++q) {
        int idx = __builtin_amdgcn_readlane(myidx, j + q);   // SGPR index
        p[q] = F[(size_t)idx * 64 + l];                      // uniform base + l*4
      }
#pragma unroll
      for (int q = 0; q < 8; ++q) { alo[q & 3] += bflo2f(p[q]); ahi[q & 3] += bfhi2f(p[q]); }
    }
    for (; j + 4 <= cnt; j += 4) {
      unsigned p[4];
#pragma unroll
      for (int q = 0; q < 4; ++q) {
        int idx = __builtin_amdgcn_readlane(myidx, j + q);
        p[q] = F[(size_t)idx * 64 + l];
      }
#pragma unroll
      for (int q = 0; q < 4; ++q) { alo[q] += bflo2f(p[q]); ahi[q] += bfhi2f(p[q]); }
    }
    for (; j < cnt; ++j) {
      int idx = __builtin_amdgcn_readlane(myidx, j);
      unsigned p = F[(size_t)idx * 64 + l];
      alo[0] += bflo2f(p); ahi[0] += bfhi2f(p);
    }
  }

  float a0 = (alo[0] + alo[1]) + (alo[2] + alo[3]);
  float a1 = (ahi[0] + ahi[1]) + (ahi[2] + ahi[3]);
  float inv = 1.0f / (float)(dg > 0 ? dg : 1);
  a0 *= inv; a1 *= inv;
  unsigned pk = ((unsigned)f2bf(a1) << 16) | f2bf(a0);
  ((unsigned*)hbuf)[(rowbase(b) + v) * 64 + l] = pk;
}

// ---- R4(new): inverse merge index build (in freed csr region) ----
__global__ __launch_bounds__(256) void inv_zero(int* __restrict__ inv) {
  inv[blockIdx.x * 256 + threadIdx.x] = 0;   // 12*NN entries
}
__global__ __launch_bounds__(256) void inv_scatter(const int* __restrict__ merge,
                                                   int* __restrict__ inv) {
  int i = blockIdx.x * 256 + threadIdx.x;    // 12*MM entries
  int p = i >> 15;                            // off-diag pair 0..11 (s-major, d asc skip diag)
  int m = i & (MM - 1);
  int s = p / 3;
  int dd = p % 3;
  int d = dd + (dd >= s ? 1 : 0);
  int u = merge[((size_t)(s * PN + d)) * MM + m];
  inv[p * NN + u] = m + 1;
}

// ---- fused GEMM: diag block + gathered off-diag merge, write-once output ----
// For out tile rows v of partition d: acc = feats[d][v]@Ws[d] + hbuf_diag[v]@Wn[d]
// + for each s!=d with m=inv[offb][v]-1 >= 0:
//     feats[s][m]@Ws[s] + hbuf[(s,d)][m]@Wn[s]  (zero A-rows where no merge entry)
// Replaces 3 rounds of 384 MB random 512B RMW with 192 MB of random gathers.
// mfma_f32_16x16x32_bf16: A[m=l&15][k=(l>>4)*8+j], B[k][n=l&15], C col=l&15, row=(l>>4)*4+reg
__global__ __launch_bounds__(256) void gemm_kernel(const unsigned short* __restrict__ featsbf,
                                                   const unsigned short* __restrict__ hbuf,
                                                   const unsigned short* __restrict__ Wpack,
                                                   const float* __restrict__ bias,
                                                   const int* __restrict__ inv,
                                                   float* __restrict__ out) {
  int w = threadIdx.x >> 6;
  int l = threadIdx.x & 63;
  int d = blockIdx.y;
  int row0 = blockIdx.x * 64;
  int kq = l >> 4;
  int m16 = l & 15;
  int n0 = w * 32;

  floatx4 acc[4][2];
#pragma unroll
  for (int rt = 0; rt < 4; ++rt)
#pragma unroll
    for (int t = 0; t < 2; ++t) acc[rt][t] = (floatx4){0.f, 0.f, 0.f, 0.f};

  // ---- diagonal block (s = d) ----
  {
    int b = 5 * d;
    const unsigned short* Aself = featsbf + (size_t)d * NN * DD;
    const unsigned short* Ah = hbuf + (size_t)rowbase(b) * DD;
    short8 bfrag[2][4][2];
#pragma unroll
    for (int mat = 0; mat < 2; ++mat) {
      const unsigned short* WT = Wpack + ((size_t)(mat * PN + d) * OO) * DD;
#pragma unroll
      for (int kk = 0; kk < 4; ++kk)
#pragma unroll
        for (int t = 0; t < 2; ++t) {
          int col = n0 + 16 * t + m16;
          bfrag[mat][kk][t] =
              *reinterpret_cast<const short8*>(WT + (size_t)col * DD + kk * 32 + kq * 8);
        }
    }
#pragma unroll
    for (int mat = 0; mat < 2; ++mat) {
      const unsigned short* A = mat ? Ah : Aself;
#pragma unroll
      for (int kk = 0; kk < 4; ++kk)
#pragma unroll
        for (int rt = 0; rt < 4; ++rt) {
          int row = row0 + rt * 16 + m16;
          short8 af = *reinterpret_cast<const short8*>(A + (size_t)row * DD + kk * 32 + kq * 8);
          acc[rt][0] = __builtin_amdgcn_mfma_f32_16x16x32_bf16(af, bfrag[mat][kk][0], acc[rt][0], 0, 0, 0);
          acc[rt][1] = __builtin_amdgcn_mfma_f32_16x16x32_bf16(af, bfrag[mat][kk][1], acc[rt][1], 0, 0, 0);
        }
    }
  }

  // ---- off-diagonal merged contributions (gathered A rows) ----
  int invj[3][4];
  float bj0[3], bj1[3];
#pragma unroll
  for (int j = 0; j < 3; ++j) {
    int s = j + (j >= d ? 1 : 0);
    int b = s * 4 + d;
    int p = offidx(b);
    const int* invp = inv + (size_t)p * NN;
#pragma unroll
    for (int rt = 0; rt < 4; ++rt) invj[j][rt] = invp[row0 + rt * 16 + m16];
    bj0[j] = bias[s * OO + n0 + m16];
    bj1[j] = bias[s * OO + n0 + 16 + m16];

    const unsigned short* As = featsbf + (size_t)s * NN * DD;
    const unsigned short* Hs = hbuf + (size_t)rowbase(b) * DD;
    short8 bfrag[2][4][2];
#pragma unroll
    for (int mat = 0; mat < 2; ++mat) {
      const unsigned short* WT = Wpack + ((size_t)(mat * PN + s) * OO) * DD;
#pragma unroll
      for (int kk = 0; kk < 4; ++kk)
#pragma unroll
        for (int t = 0; t < 2; ++t) {
          int col = n0 + 16 * t + m16;
          bfrag[mat][kk][t] =
              *reinterpret_cast<const short8*>(WT + (size_t)col * DD + kk * 32 + kq * 8);
        }
    }
#pragma unroll
    for (int mat = 0; mat < 2; ++mat) {
      const unsigned short* A = mat ? Hs : As;
#pragma unroll
      for (int kk = 0; kk < 4; ++kk)
#pragma unroll
        for (int rt = 0; rt < 4; ++rt) {
          int idx = invj[j][rt];
          short8 af = (short8){0, 0, 0, 0, 0, 0, 0, 0};
          if (idx > 0)
            af = *reinterpret_cast<const short8*>(A + (size_t)(idx - 1) * DD + kk * 32 + kq * 8);
          acc[rt][0] = __builtin_amdgcn_mfma_f32_16x16x32_bf16(af, bfrag[mat][kk][0], acc[rt][0], 0, 0, 0);
          acc[rt][1] = __builtin_amdgcn_mfma_f32_16x16x32_bf16(af, bfrag[mat][kk][1], acc[rt][1], 0, 0, 0);
        }
    }
  }

  // ---- epilogue: bias (diag always, off-diag where merged), single store ----
  float bs0 = bias[d * OO + n0 + m16];
  float bs1 = bias[d * OO + n0 + 16 + m16];
  float* outd = out + (size_t)d * NN * OO;
#pragma unroll
  for (int rt = 0; rt < 4; ++rt) {
#pragma unroll
    for (int r = 0; r < 4; ++r) {
      int row = row0 + rt * 16 + kq * 4 + r;
      float v0 = acc[rt][0][r] + bs0;
      float v1 = acc[rt][1][r] + bs1;
#pragma unroll
      for (int j = 0; j < 3; ++j) {
        int iv = __shfl(invj[j][rt], kq * 4 + r);   // inv value for this C-row
        if (iv > 0) { v0 += bj0[j]; v1 += bj1[j]; }
      }
      outd[(size_t)row * OO + n0 + m16] = v0;
      outd[(size_t)row * OO + n0 + 16 + m16] = v1;
    }
  }
}

extern "C" void kernel_launch(void* const* d_in, const int* in_sizes, int n_in,
                              void* d_out, int out_size, void* d_ws, size_t ws_size,
                              hipStream_t stream) {
  const float* feats = (const float*)d_in[0];
  const float* Wself = (const float*)d_in[1];
  const float* Wneigh = (const float*)d_in[2];
  const float* bias = (const float*)d_in[3];
  const int* esrc = (const int*)d_in[4];
  const int* edst = (const int*)d_in[5];
  const int* merge = (const int*)d_in[6];
  float* out = (float*)d_out;

  char* ws = (char*)d_ws;
  unsigned short* featsbf = (unsigned short*)(ws);               // 67,108,864
  int* deg   = (int*)(ws + 67108864);                            //  4,194,304
  int* offs  = (int*)(ws + 71303168);                            //  4,194,304
  int* csr   = (int*)(ws + 75497472);                            // 32,000,000
  unsigned short* hbuf = (unsigned short*)(ws + 107497472);      // 167,772,160 (ends 275,269,632)
  unsigned short* Wpack = (unsigned short*)(ws + 275269632);     //     262,144
  int* btot  = (int*)(ws + 275531776);                           //      16,384
  int* bbase = (int*)(ws + 275548160);                           //      16,384 (total 275,564,544)
  // overlays inside hbuf region (consumed before agg writes hbuf):
  uint2* tmp = (uint2*)(ws + 107497472);                         //  64,000,000
  int* mat   = (int*)(ws + 107497472 + 64000000);                //  16,056,320
  // overlay in csr region (csr dead after agg; inv built after agg):
  int* inv   = (int*)(ws + 75497472);                            //   3,145,728 (12*NN*4)

  cvt_kernel<<<(PN * NN * DD) / 4 / 256, 256, 0, stream>>>(feats, featsbf);
  packW_kernel<<<512, 256, 0, stream>>>(Wself, Wneigh, Wpack);
  bucket_count<<<dim3(NW, 16), 256, 0, stream>>>(edst, mat);
  bucket_colscan<<<1024, 256, 0, stream>>>(mat, btot);
  bucket_base<<<16, 256, 0, stream>>>(btot, bbase);
  bucket_scatter<<<dim3(NW, 16), 256, 0, stream>>>(esrc, edst, mat, bbase, tmp);
  csr_build<<<dim3(256, 16), 256, 0, stream>>>(tmp, btot, bbase, deg, offs, csr);
  agg_kernel<<<dim3(NN / 4, 16), 256, 0, stream>>>(featsbf, csr, offs, deg, hbuf);
  inv_zero<<<12 * NN / 256, 256, 0, stream>>>(inv);
  inv_scatter<<<12 * MM / 256, 256, 0, stream>>>(merge, inv);
  gemm_kernel<<<dim3(NN / 64, 4), 256, 0, stream>>>(featsbf, hbuf, Wpack, bias, inv, out);
}

// Round 5
// 932.622 us; speedup vs baseline: 1.1802x; 1.1802x over previous
//
#include <hip/hip_runtime.h>
#include <stdint.h>

#define PN 4
#define NN 65536
#define DD 128
#define OO 128
#define EE 500000
#define MM 32768
#define NW 245       // WGs per block for bucketing: ceil(500000/2048)

typedef __attribute__((ext_vector_type(8))) short short8;
typedef __attribute__((ext_vector_type(4))) float floatx4;
typedef __attribute__((ext_vector_type(4))) float f4v;
typedef __attribute__((ext_vector_type(2))) unsigned u2v;

__device__ __forceinline__ unsigned short f2bf(float f) {
  unsigned u = __float_as_uint(f);
  u += 0x7fffu + ((u >> 16) & 1u);
  return (unsigned short)(u >> 16);
}
__device__ __forceinline__ float bfhi2f(unsigned u) { return __uint_as_float(u & 0xffff0000u); }
__device__ __forceinline__ float bflo2f(unsigned u) { return __uint_as_float(u << 16); }

// block b = s*4+d; diag blocks are b in {0,5,10,15}
__device__ __forceinline__ long rowbase(int b) {
  int diagb = (b + 4) / 5;
  int offb = b - diagb;
  return (long)diagb * NN + (long)offb * MM;
}
__device__ __forceinline__ int offidx(int b) { return b - (b + 4) / 5; }  // 0..11 for off-diag b

// ---- fp32 -> bf16 conversion of feats ----
__global__ __launch_bounds__(256) void cvt_kernel(const float* __restrict__ f,
                                                  unsigned short* __restrict__ o) {
  size_t i = (size_t)blockIdx.x * blockDim.x + threadIdx.x;
  f4v v = __builtin_nontemporal_load((const f4v*)f + i);
  uint2 r;
  r.x = ((unsigned)f2bf(v[1]) << 16) | f2bf(v[0]);
  r.y = ((unsigned)f2bf(v[3]) << 16) | f2bf(v[2]);
  ((uint2*)o)[i] = r;   // featsbf: keep cached (heavy downstream reuse)
}

// ---- pack W_self/W_neigh to bf16, col-major [mat][s][col][k] ----
__global__ __launch_bounds__(256) void packW_kernel(const float* __restrict__ Ws,
                                                    const float* __restrict__ Wn,
                                                    unsigned short* __restrict__ Wp) {
  int i = blockIdx.x * 256 + threadIdx.x;   // 2*4*128*128 = 131072
  int k = i & 127;
  int col = (i >> 7) & 127;
  int s = (i >> 14) & 3;
  int mat = i >> 16;
  const float* W = mat ? Wn : Ws;
  Wp[i] = f2bf(W[((size_t)s * DD + k) * OO + col]);
}

// ---- R1: per-WG coarse histogram (dst>>8), LDS only, coalesced matrix write ----
__global__ __launch_bounds__(256) void bucket_count(const int* __restrict__ edst,
                                                    int* __restrict__ mat) {
  __shared__ int hist[256];
  int b = blockIdx.y, w = blockIdx.x, t = threadIdx.x;
  hist[t] = 0;
  __syncthreads();
  size_t ebase = (size_t)b * EE;
#pragma unroll
  for (int k = 0; k < 8; ++k) {
    int e = w * 2048 + k * 256 + t;
    if (e < EE) atomicAdd(&hist[edst[ebase + e] >> 8], 1);
  }
  __syncthreads();
  mat[((size_t)b * NW + w) * 256 + t] = hist[t];
}

// ---- R2a: exclusive scan of mat over WG axis (per b,beta); totals per bucket ----
__global__ __launch_bounds__(256) void bucket_colscan(int* __restrict__ mat,
                                                      int* __restrict__ btot) {
  int t = threadIdx.x;
  int wid = blockIdx.x * 4 + (t >> 6);   // 4096 waves = 16 b * 256 beta
  int l = t & 63;
  int b = wid >> 8, beta = wid & 255;
  int run = 0;
  for (int c = 0; c < 4; ++c) {
    int w = c * 64 + l;
    size_t idx = ((size_t)b * NW + w) * 256 + beta;
    int v = (w < NW) ? mat[idx] : 0;
    int x = v;
#pragma unroll
    for (int off = 1; off < 64; off <<= 1) {
      int y = __shfl_up(x, off);
      if (l >= off) x += y;
    }
    if (w < NW) mat[idx] = run + x - v;
    run += __shfl(x, 63);
  }
  if (l == 0) btot[b * 256 + beta] = run;
}

// ---- R2b: per-block exclusive scan of 256 bucket totals -> bucket bases ----
__global__ __launch_bounds__(256) void bucket_base(const int* __restrict__ btot,
                                                   int* __restrict__ bbase) {
  __shared__ int sc[256];
  int b = blockIdx.x, t = threadIdx.x;
  int v = btot[b * 256 + t];
  sc[t] = v;
  __syncthreads();
  for (int off = 1; off < 256; off <<= 1) {
    int x = (t >= off) ? sc[t - off] : 0;
    __syncthreads();
    sc[t] += x;
    __syncthreads();
  }
  bbase[b * 256 + t] = sc[t] - v;
}

// ---- R3: scatter edges into coarse-bucket-sorted tmp via LDS cursors ----
__global__ __launch_bounds__(256) void bucket_scatter(const int* __restrict__ esrc,
                                                      const int* __restrict__ edst,
                                                      const int* __restrict__ mat,
                                                      const int* __restrict__ bbase,
                                                      uint2* __restrict__ tmp) {
  __shared__ int cur[256];
  int b = blockIdx.y, w = blockIdx.x, t = threadIdx.x;
  cur[t] = bbase[b * 256 + t] + mat[((size_t)b * NW + w) * 256 + t];
  __syncthreads();
  size_t ebase = (size_t)b * EE;
#pragma unroll
  for (int k = 0; k < 8; ++k) {
    int e = w * 2048 + k * 256 + t;
    if (e < EE) {
      int dv = __builtin_nontemporal_load(&edst[ebase + e]);
      int sv = __builtin_nontemporal_load(&esrc[ebase + e]);
      int p = atomicAdd(&cur[dv >> 8], 1);
      tmp[ebase + p] = (uint2){(unsigned)dv, (unsigned)sv};
    }
  }
}

// ---- R4: per (b, coarse bucket): fine CSR + deg + offs, all LDS-local ----
__global__ __launch_bounds__(256) void csr_build(const uint2* __restrict__ tmp,
                                                 const int* __restrict__ btot,
                                                 const int* __restrict__ bbase,
                                                 int* __restrict__ deg,
                                                 int* __restrict__ offs,
                                                 int* __restrict__ csr) {
  __shared__ int hist[256], sc[256], cur[256];
  int b = blockIdx.y, beta = blockIdx.x, t = threadIdx.x;
  int cnt = btot[b * 256 + beta];
  int segbase = bbase[b * 256 + beta];
  hist[t] = 0;
  __syncthreads();
  size_t tbase = (size_t)b * EE + segbase;
  for (int i = t; i < cnt; i += 256) atomicAdd(&hist[tmp[tbase + i].x & 255], 1);
  __syncthreads();
  sc[t] = hist[t];
  __syncthreads();
  for (int off = 1; off < 256; off <<= 1) {
    int x = (t >= off) ? sc[t - off] : 0;
    __syncthreads();
    sc[t] += x;
    __syncthreads();
  }
  int excl = sc[t] - hist[t];
  int v = beta * 256 + t;
  deg[b * NN + v] = hist[t];
  offs[b * NN + v] = segbase + excl;
  cur[t] = excl;
  __syncthreads();
  const u2v* tp = (const u2v*)tmp;
  for (int i = t; i < cnt; i += 256) {
    u2v pr = __builtin_nontemporal_load(tp + tbase + i);
    int p = atomicAdd(&cur[pr[0] & 255], 1);
    csr[(size_t)b * EE + segbase + p] = (int)pr[1];
  }
}

// ---- mean aggregation: one wave per dst row ----
// At structural roofline: 834 MB random-256B fetch @ ~3.4 TB/s. Do not touch.
__global__ __launch_bounds__(256) void agg_kernel(const unsigned short* __restrict__ featsbf,
                                                  const int* __restrict__ csr,
                                                  const int* __restrict__ offs,
                                                  const int* __restrict__ deg,
                                                  unsigned short* __restrict__ hbuf) {
  int b = blockIdx.y;
  int s = b >> 2, d = b & 3;
  int num_dst = (s == d) ? NN : MM;
  int v = blockIdx.x * 4 + (threadIdx.x >> 6);
  if (v >= num_dst) return;
  int l = threadIdx.x & 63;
  const unsigned* F = (const unsigned*)(featsbf + (size_t)s * NN * DD);
  int o  = __builtin_amdgcn_readfirstlane(offs[b * NN + v]);
  int dg = __builtin_amdgcn_readfirstlane(deg[b * NN + v]);
  const int* cs = csr + (size_t)b * EE + o;   // wave-uniform pointer

  float alo[4] = {0.f, 0.f, 0.f, 0.f};
  float ahi[4] = {0.f, 0.f, 0.f, 0.f};

  for (int base = 0; base < dg; base += 64) {
    int rem = dg - base;
    int cnt = rem < 64 ? rem : 64;
    int myidx = (l < cnt) ? cs[base + l] : 0;
    int j = 0;
    for (; j + 8 <= cnt; j += 8) {
      unsigned p[8];
#pragma unroll
      for (int q = 0; q < 8; ++q) {
        int idx = __builtin_amdgcn_readlane(myidx, j + q);   // SGPR index
        p[q] = F[(size_t)idx * 64 + l];                      // uniform base + l*4
      }
#pragma unroll
      for (int q = 0; q < 8; ++q) { alo[q & 3] += bflo2f(p[q]); ahi[q & 3] += bfhi2f(p[q]); }
    }
    for (; j + 4 <= cnt; j += 4) {
      unsigned p[4];
#pragma unroll
      for (int q = 0; q < 4; ++q) {
        int idx = __builtin_amdgcn_readlane(myidx, j + q);
        p[q] = F[(size_t)idx * 64 + l];
      }
#pragma unroll
      for (int q = 0; q < 4; ++q) { alo[q] += bflo2f(p[q]); ahi[q] += bfhi2f(p[q]); }
    }
    for (; j < cnt; ++j) {
      int idx = __builtin_amdgcn_readlane(myidx, j);
      unsigned p = F[(size_t)idx * 64 + l];
      alo[0] += bflo2f(p); ahi[0] += bfhi2f(p);
    }
  }

  float a0 = (alo[0] + alo[1]) + (alo[2] + alo[3]);
  float a1 = (ahi[0] + ahi[1]) + (ahi[2] + ahi[3]);
  float inv = 1.0f / (float)(dg > 0 ? dg : 1);
  a0 *= inv; a1 *= inv;
  unsigned pk = ((unsigned)f2bf(a1) << 16) | f2bf(a0);
  ((unsigned*)hbuf)[(rowbase(b) + v) * 64 + l] = pk;
}

// ---- inverse merge index build (in freed csr region) ----
__global__ __launch_bounds__(256) void inv_zero(int* __restrict__ inv) {
  inv[blockIdx.x * 256 + threadIdx.x] = 0;   // 12*NN entries
}
__global__ __launch_bounds__(256) void inv_scatter(const int* __restrict__ merge,
                                                   int* __restrict__ inv) {
  int i = blockIdx.x * 256 + threadIdx.x;    // 12*MM entries
  int p = i >> 15;                            // off-diag pair 0..11 (s-major, d asc skip diag)
  int m = i & (MM - 1);
  int s = p / 3;
  int dd = p % 3;
  int d = dd + (dd >= s ? 1 : 0);
  int u = merge[((size_t)(s * PN + d)) * MM + m];
  inv[p * NN + u] = m + 1;
}

// ---- fused GEMM v2: diag block streaming + LDS-staged gathered off-diag merge ----
// R4 post-mortem: per-lane divergent row gathers into MFMA fragments = 16
// cache lines per load instruction -> 407us latency disaster. Fix: gather
// merged rows with 64-lane COALESCED 256B row loads (agg's proven 3.4 TB/s
// pattern) into XOR-swizzled LDS; MFMA fragments read from LDS conflict-free.
// Swizzle: dword di = r*64 + (l ^ ((r&7)<<2)); read short8 at byte
// (kk*64+kq*16) ^ ((row&7)<<4). Banks: read = 8 accesses/bank (minimum),
// write = 2-way (free).
__global__ __launch_bounds__(256) void gemm_kernel(const unsigned short* __restrict__ featsbf,
                                                   const unsigned short* __restrict__ hbuf,
                                                   const unsigned short* __restrict__ Wpack,
                                                   const float* __restrict__ bias,
                                                   const int* __restrict__ inv,
                                                   float* __restrict__ out) {
  __shared__ unsigned short Abuf[64 * 128];   // 16 KB
  __shared__ unsigned short Hbuf[64 * 128];   // 16 KB
  int tid = threadIdx.x;
  int w = __builtin_amdgcn_readfirstlane(tid >> 6);
  int l = tid & 63;
  int d = blockIdx.y;
  int row0 = blockIdx.x * 64;
  int kq = l >> 4;
  int m16 = l & 15;
  int n0 = w * 32;

  floatx4 acc[4][2];
#pragma unroll
  for (int rt = 0; rt < 4; ++rt)
#pragma unroll
    for (int t = 0; t < 2; ++t) acc[rt][t] = (floatx4){0.f, 0.f, 0.f, 0.f};

  // ---- diagonal block (s = d): streaming, rows consecutive (L1-friendly) ----
  {
    int b = 5 * d;
    const unsigned short* Aself = featsbf + (size_t)d * NN * DD;
    const unsigned short* Ah = hbuf + (size_t)rowbase(b) * DD;
    short8 bfrag[2][4][2];
#pragma unroll
    for (int mat = 0; mat < 2; ++mat) {
      const unsigned short* WT = Wpack + ((size_t)(mat * PN + d) * OO) * DD;
#pragma unroll
      for (int kk = 0; kk < 4; ++kk)
#pragma unroll
        for (int t = 0; t < 2; ++t) {
          int col = n0 + 16 * t + m16;
          bfrag[mat][kk][t] =
              *reinterpret_cast<const short8*>(WT + (size_t)col * DD + kk * 32 + kq * 8);
        }
    }
#pragma unroll
    for (int mat = 0; mat < 2; ++mat) {
      const unsigned short* A = mat ? Ah : Aself;
#pragma unroll
      for (int kk = 0; kk < 4; ++kk)
#pragma unroll
        for (int rt = 0; rt < 4; ++rt) {
          int row = row0 + rt * 16 + m16;
          short8 af = *reinterpret_cast<const short8*>(A + (size_t)row * DD + kk * 32 + kq * 8);
          acc[rt][0] = __builtin_amdgcn_mfma_f32_16x16x32_bf16(af, bfrag[mat][kk][0], acc[rt][0], 0, 0, 0);
          acc[rt][1] = __builtin_amdgcn_mfma_f32_16x16x32_bf16(af, bfrag[mat][kk][1], acc[rt][1], 0, 0, 0);
        }
    }
  }

  // ---- off-diagonal merged contributions: LDS-staged coalesced gathers ----
  int ivvj[3];                 // lane l holds inv value for tile-row l
  float bj0[3], bj1[3];
#pragma unroll
  for (int j = 0; j < 3; ++j) {
    int s = j + (j >= d ? 1 : 0);
    int b = s * 4 + d;
    const int* invp = inv + (size_t)offidx(b) * NN;
    int ivv = invp[row0 + l];
    ivvj[j] = ivv;
    bj0[j] = bias[s * OO + n0 + m16];
    bj1[j] = bias[s * OO + n0 + 16 + m16];

    const unsigned* Fs = (const unsigned*)(featsbf + (size_t)s * NN * DD);
    const unsigned* Hs = (const unsigned*)(hbuf + (size_t)rowbase(b) * DD);

    // gather: wave w owns tile-rows w*16..w*16+15; one coalesced 256B row
    // load per (feats,hbuf) row; unmerged rows load row 0 (L2-hot) and zero.
    unsigned av[16], hv[16];
    int ivr[16];
#pragma unroll
    for (int i = 0; i < 16; ++i) {
      int iv = __builtin_amdgcn_readlane(ivv, w * 16 + i);   // SGPR, uniform
      ivr[i] = iv;
      int m = iv > 0 ? iv - 1 : 0;
      av[i] = Fs[(size_t)m * 64 + l];                        // uniform base + l*4
      hv[i] = Hs[(size_t)m * 64 + l];
    }
#pragma unroll
    for (int i = 0; i < 16; ++i) {
      int r = w * 16 + i;
      int di = r * 64 + (l ^ ((r & 7) << 2));                // swizzled dword slot
      ((unsigned*)Abuf)[di] = ivr[i] > 0 ? av[i] : 0u;
      ((unsigned*)Hbuf)[di] = ivr[i] > 0 ? hv[i] : 0u;
    }
    __syncthreads();

    short8 bfrag[2][4][2];
#pragma unroll
    for (int mat = 0; mat < 2; ++mat) {
      const unsigned short* WT = Wpack + ((size_t)(mat * PN + s) * OO) * DD;
#pragma unroll
      for (int kk = 0; kk < 4; ++kk)
#pragma unroll
        for (int t = 0; t < 2; ++t) {
          int col = n0 + 16 * t + m16;
          bfrag[mat][kk][t] =
              *reinterpret_cast<const short8*>(WT + (size_t)col * DD + kk * 32 + kq * 8);
        }
    }
#pragma unroll
    for (int mat = 0; mat < 2; ++mat) {
      const unsigned short* Lb = mat ? Hbuf : Abuf;
#pragma unroll
      for (int kk = 0; kk < 4; ++kk)
#pragma unroll
        for (int rt = 0; rt < 4; ++rt) {
          int row = rt * 16 + m16;
          int boff = ((kk * 64 + kq * 16) ^ ((row & 7) << 4)) >> 1;  // ushort idx in row
          short8 af = *reinterpret_cast<const short8*>(&Lb[row * 128 + boff]);
          acc[rt][0] = __builtin_amdgcn_mfma_f32_16x16x32_bf16(af, bfrag[mat][kk][0], acc[rt][0], 0, 0, 0);
          acc[rt][1] = __builtin_amdgcn_mfma_f32_16x16x32_bf16(af, bfrag[mat][kk][1], acc[rt][1], 0, 0, 0);
        }
    }
    __syncthreads();
  }

  // ---- epilogue: bias (diag always, off-diag where merged), single store ----
  float bs0 = bias[d * OO + n0 + m16];
  float bs1 = bias[d * OO + n0 + 16 + m16];
  float* outd = out + (size_t)d * NN * OO;
#pragma unroll
  for (int rt = 0; rt < 4; ++rt) {
#pragma unroll
    for (int r = 0; r < 4; ++r) {
      int row = row0 + rt * 16 + kq * 4 + r;
      float v0 = acc[rt][0][r] + bs0;
      float v1 = acc[rt][1][r] + bs1;
#pragma unroll
      for (int j = 0; j < 3; ++j) {
        int iv = __shfl(ivvj[j], rt * 16 + kq * 4 + r);   // inv value for this C-row
        if (iv > 0) { v0 += bj0[j]; v1 += bj1[j]; }
      }
      outd[(size_t)row * OO + n0 + m16] = v0;
      outd[(size_t)row * OO + n0 + 16 + m16] = v1;
    }
  }
}

extern "C" void kernel_launch(void* const* d_in, const int* in_sizes, int n_in,
                              void* d_out, int out_size, void* d_ws, size_t ws_size,
                              hipStream_t stream) {
  const float* feats = (const float*)d_in[0];
  const float* Wself = (const float*)d_in[1];
  const float* Wneigh = (const float*)d_in[2];
  const float* bias = (const float*)d_in[3];
  const int* esrc = (const int*)d_in[4];
  const int* edst = (const int*)d_in[5];
  const int* merge = (const int*)d_in[6];
  float* out = (float*)d_out;

  char* ws = (char*)d_ws;
  unsigned short* featsbf = (unsigned short*)(ws);               // 67,108,864
  int* deg   = (int*)(ws + 67108864);                            //  4,194,304
  int* offs  = (int*)(ws + 71303168);                            //  4,194,304
  int* csr   = (int*)(ws + 75497472);                            // 32,000,000
  unsigned short* hbuf = (unsigned short*)(ws + 107497472);      // 167,772,160 (ends 275,269,632)
  unsigned short* Wpack = (unsigned short*)(ws + 275269632);     //     262,144
  int* btot  = (int*)(ws + 275531776);                           //      16,384
  int* bbase = (int*)(ws + 275548160);                           //      16,384 (total 275,564,544)
  // overlays inside hbuf region (consumed before agg writes hbuf):
  uint2* tmp = (uint2*)(ws + 107497472);                         //  64,000,000
  int* mat   = (int*)(ws + 107497472 + 64000000);                //  16,056,320
  // overlay in csr region (csr dead after agg; inv built after agg):
  int* inv   = (int*)(ws + 75497472);                            //   3,145,728 (12*NN*4)

  cvt_kernel<<<(PN * NN * DD) / 4 / 256, 256, 0, stream>>>(feats, featsbf);
  packW_kernel<<<512, 256, 0, stream>>>(Wself, Wneigh, Wpack);
  bucket_count<<<dim3(NW, 16), 256, 0, stream>>>(edst, mat);
  bucket_colscan<<<1024, 256, 0, stream>>>(mat, btot);
  bucket_base<<<16, 256, 0, stream>>>(btot, bbase);
  bucket_scatter<<<dim3(NW, 16), 256, 0, stream>>>(esrc, edst, mat, bbase, tmp);
  csr_build<<<dim3(256, 16), 256, 0, stream>>>(tmp, btot, bbase, deg, offs, csr);
  agg_kernel<<<dim3(NN / 4, 16), 256, 0, stream>>>(featsbf, csr, offs, deg, hbuf);
  inv_zero<<<12 * NN / 256, 256, 0, stream>>>(inv);
  inv_scatter<<<12 * MM / 256, 256, 0, stream>>>(merge, inv);
  gemm_kernel<<<dim3(NN / 64, 4), 256, 0, stream>>>(featsbf, hbuf, Wpack, bias, inv, out);
}